// Round 9
// baseline (64.384 us; speedup 1.0000x reference)
//
#include <hip/hip_runtime.h>
#include <hip/hip_bf16.h>

#define N_NODES 4096
#define F_IN 512
#define FHD 64
#define H_HEADS 8
#define C_OUT 512   /* H*FH */
#define ALPHA 0.2f
#define MAXE 192

typedef __attribute__((ext_vector_type(8))) short bf16x8;
typedef __attribute__((ext_vector_type(4))) float f32x4;

static __device__ __forceinline__ unsigned short f2bf(float f) {
  __hip_bfloat16 h = __float2bfloat16(f);
  union { __hip_bfloat16 h; unsigned short u; } cvt;
  cvt.h = h;
  return cvt.u;
}
static __device__ __forceinline__ float bf2f(unsigned short u) {
  return __uint_as_float(((unsigned)u) << 16);
}

// ---------------------------------------------------------------------------
// stream: all pure-streaming, mutually independent work in ONE launch.
// blocks [0,4096)      : A-row CSR scan (dominant: 67 MB)
// blocks [4096,6144)   : X -> bf16
// blocks [6144,6208)   : W -> bf16 transposed [h][o][f]
// block  6208          : zero colsum
// Scan blocks first so A-reads saturate HBM from t=0.
// ---------------------------------------------------------------------------
__global__ __launch_bounds__(256) void stream_kernel(
    const float* __restrict__ A, const float* __restrict__ X,
    const float* __restrict__ W, unsigned short* __restrict__ edges,
    int* __restrict__ degs, unsigned short* __restrict__ Xb,
    unsigned short* __restrict__ WbT, float* __restrict__ colsum) {
  __shared__ int wave_tot[4];
  __shared__ float sT[64][65];
  const int bid = blockIdx.x;
  const int tid = threadIdx.x;

  if (bid < N_NODES) {
    // ---- CSR scan: thread owns 16 consecutive elements of A's row
    const int i = bid;
    const int wid = tid >> 6, lane = tid & 63;
    const float4* __restrict__ Arow4 =
        reinterpret_cast<const float4*>(A + (size_t)i * N_NODES);
    float4 v[4];
#pragma unroll
    for (int q = 0; q < 4; ++q) v[q] = Arow4[tid * 4 + q];
    int mask16 = 0;
#pragma unroll
    for (int q = 0; q < 4; ++q) {
      mask16 |= (v[q].x != 0.f) ? (1 << (q * 4 + 0)) : 0;
      mask16 |= (v[q].y != 0.f) ? (1 << (q * 4 + 1)) : 0;
      mask16 |= (v[q].z != 0.f) ? (1 << (q * 4 + 2)) : 0;
      mask16 |= (v[q].w != 0.f) ? (1 << (q * 4 + 3)) : 0;
    }
    int cnt = __popc(mask16);
    int inc = cnt;
#pragma unroll
    for (int s = 1; s < 64; s <<= 1) {
      int t = __shfl_up(inc, s, 64);
      if (lane >= s) inc += t;
    }
    if (lane == 63) wave_tot[wid] = inc;
    __syncthreads();
    int wprefix = 0, tot = 0;
#pragma unroll
    for (int w = 0; w < 4; ++w) {
      int t = wave_tot[w];
      if (w < wid) wprefix += t;
      tot += t;
    }
    int pos = wprefix + inc - cnt;
    const int jbase = tid * 16;
    unsigned short* __restrict__ erow = edges + (size_t)i * MAXE;
    while (mask16) {
      int k = __ffs(mask16) - 1;
      mask16 &= mask16 - 1;
      if (pos < MAXE) erow[pos] = (unsigned short)(jbase + k);
      ++pos;
    }
    if (tid == 0) degs[i] = tot < MAXE ? tot : MAXE;
  } else if (bid < N_NODES + 2048) {
    // ---- convX: f32 -> bf16, 4 elems/thread
    int idx = (bid - N_NODES) * 256 + tid;
    float4 v = reinterpret_cast<const float4*>(X)[idx];
    ushort4 u;
    u.x = f2bf(v.x); u.y = f2bf(v.y); u.z = f2bf(v.z); u.w = f2bf(v.w);
    reinterpret_cast<ushort4*>(Xb)[idx] = u;
  } else if (bid < N_NODES + 2048 + 64) {
    // ---- convW: W[h][f][o] f32 -> WbT[h][o][f] bf16
    const int b2 = bid - (N_NODES + 2048);
    const int fblk = b2 & 7, h = b2 >> 3;
#pragma unroll
    for (int i = 0; i < 16; ++i) {
      int idx = tid + i * 256;
      int f = idx >> 6, o = idx & 63;
      sT[f][o] = W[((size_t)h * F_IN + fblk * 64 + f) * FHD + o];
    }
    __syncthreads();
#pragma unroll
    for (int i = 0; i < 16; ++i) {
      int idx = tid + i * 256;
      int o = idx >> 6, f = idx & 63;
      WbT[(size_t)h * FHD * F_IN + (size_t)o * F_IN + fblk * 64 + f] =
          f2bf(sT[f][o]);
    }
  } else {
    colsum[tid] = 0.f;
    colsum[tid + 256] = 0.f;
  }
}

// ---------------------------------------------------------------------------
// MFMA GEMM: 64 rows x 1 head per block, BK=64, grid (64,8)=512 blocks.
// Fused: s_self/s_neigh scores + colsum partials (atomicAdd).
// A frag: row=l&15, k=(l>>4)*8+j ; B frag: col=l&15, k=(l>>4)*8+j
// C/D:    col=l&15, row=(l>>4)*4+reg   [m89/m91-verified]
// ---------------------------------------------------------------------------
__global__ __launch_bounds__(256) void gemm_feats_mfma_kernel(
    const unsigned short* __restrict__ Xb, const unsigned short* __restrict__ WbT,
    const float* __restrict__ a_self, const float* __restrict__ a_neigh,
    unsigned short* __restrict__ featsb,
    float* __restrict__ s_self, float* __restrict__ s_neigh,
    float* __restrict__ colsum) {
  const int h = blockIdx.y;
  const int n0 = blockIdx.x * 64;
  __shared__ unsigned short sX[2][64 * 72];  // k padded 64->72 (16B-aligned)
  __shared__ unsigned short sW[2][64 * 72];
  __shared__ float sred[4][64];
  const int tid = threadIdx.x;
  const int wid = tid >> 6, lane = tid & 63;
  const int l15 = lane & 15, l4 = lane >> 4;

  const int row = tid >> 2, seg = (tid & 3) * 16;
  const unsigned short* xsrc = Xb + (size_t)(n0 + row) * F_IN + seg;
  const unsigned short* wsrc = WbT + ((size_t)h * FHD + row) * F_IN + seg;
  const int soff = row * 72 + seg;

  f32x4 acc[4];
#pragma unroll
  for (int j = 0; j < 4; ++j) acc[j] = (f32x4){0.f, 0.f, 0.f, 0.f};

  *(bf16x8*)&sX[0][soff] = *(const bf16x8*)(xsrc);
  *(bf16x8*)&sX[0][soff + 8] = *(const bf16x8*)(xsrc + 8);
  *(bf16x8*)&sW[0][soff] = *(const bf16x8*)(wsrc);
  *(bf16x8*)&sW[0][soff + 8] = *(const bf16x8*)(wsrc + 8);
  __syncthreads();

  int cur = 0;
  for (int s = 0; s < 8; ++s) {
    bf16x8 px0, px1, pw0, pw1;
    const bool pf = (s < 7);
    if (pf) {
      const int k = (s + 1) * 64;
      px0 = *(const bf16x8*)(xsrc + k);
      px1 = *(const bf16x8*)(xsrc + k + 8);
      pw0 = *(const bf16x8*)(wsrc + k);
      pw1 = *(const bf16x8*)(wsrc + k + 8);
    }
#pragma unroll
    for (int kk = 0; kk < 2; ++kk) {
      bf16x8 a = *(const bf16x8*)&sX[cur][(wid * 16 + l15) * 72 + kk * 32 + l4 * 8];
#pragma unroll
      for (int tn = 0; tn < 4; ++tn) {
        bf16x8 b = *(const bf16x8*)&sW[cur][(tn * 16 + l15) * 72 + kk * 32 + l4 * 8];
        acc[tn] =
            __builtin_amdgcn_mfma_f32_16x16x32_bf16(a, b, acc[tn], 0, 0, 0);
      }
    }
    if (pf) {
      *(bf16x8*)&sX[cur ^ 1][soff] = px0;
      *(bf16x8*)&sX[cur ^ 1][soff + 8] = px1;
      *(bf16x8*)&sW[cur ^ 1][soff] = pw0;
      *(bf16x8*)&sW[cur ^ 1][soff + 8] = pw1;
      __syncthreads();
      cur ^= 1;
    }
  }

  float aS[4], aN[4];
#pragma unroll
  for (int tn = 0; tn < 4; ++tn) {
    aS[tn] = a_self[h * FHD + tn * 16 + l15];
    aN[tn] = a_neigh[h * FHD + tn * 16 + l15];
  }
#pragma unroll
  for (int r = 0; r < 4; ++r) {
    const int grow = n0 + wid * 16 + l4 * 4 + r;
#pragma unroll
    for (int tn = 0; tn < 4; ++tn)
      featsb[(size_t)grow * C_OUT + h * FHD + tn * 16 + l15] =
          f2bf(acc[tn][r]);
    float ps = 0.f, pn = 0.f;
#pragma unroll
    for (int tn = 0; tn < 4; ++tn) {
      float v = acc[tn][r];
      ps = fmaf(v, aS[tn], ps);
      pn = fmaf(v, aN[tn], pn);
    }
#pragma unroll
    for (int sh = 1; sh < 16; sh <<= 1) {
      ps += __shfl_xor(ps, sh, 64);
      pn += __shfl_xor(pn, sh, 64);
    }
    if (l15 == 0) {
      s_self[grow * 8 + h] = ps;
      s_neigh[grow * 8 + h] = pn;
    }
  }

  float psum[4];
#pragma unroll
  for (int tn = 0; tn < 4; ++tn) {
    float s = acc[tn][0] + acc[tn][1] + acc[tn][2] + acc[tn][3];
    s += __shfl_xor(s, 16, 64);
    s += __shfl_xor(s, 32, 64);
    psum[tn] = s;
  }
  if (l4 == 0) {
#pragma unroll
    for (int tn = 0; tn < 4; ++tn) sred[wid][tn * 16 + l15] = psum[tn];
  }
  __syncthreads();
  if (tid < 64) {
    float s = sred[0][tid] + sred[1][tid] + sred[2][tid] + sred[3][tid];
    atomicAdd(&colsum[h * FHD + tid], s);
  }
}

// ---------------------------------------------------------------------------
// attn v2: 512 threads/block, one block per row i; CSR pre-built.
// Gather phase splits edges 2-way (tid>>8) to halve the serial critical
// path; partials combined through LDS.
// ---------------------------------------------------------------------------
__global__ __launch_bounds__(512) void attn_kernel(
    const unsigned short* __restrict__ edges, const int* __restrict__ degs,
    const unsigned short* __restrict__ featsb,
    const float* __restrict__ s_self, const float* __restrict__ s_neigh,
    const float* __restrict__ colsum, const float* __restrict__ bias,
    float* __restrict__ out) {
  const int i = blockIdx.x;
  const int tid = threadIdx.x;
  const int wid = tid >> 6, lane = tid & 63;
  __shared__ int s_idx[MAXE];
  __shared__ float s_w[MAXE][9];
  __shared__ float sh_self[8];
  __shared__ float sh_e0[8], sh_invZ[8];
  __shared__ float s_part[256][2];

  const int deg = degs[i];
  if (tid < 8) sh_self[tid] = s_self[i * 8 + tid];
  if (tid < deg) s_idx[tid] = edges[(size_t)i * MAXE + tid];
  __syncthreads();

  // logits per (edge, head)
  for (int k = tid; k < deg * 8; k += 512) {
    int e = k >> 3, h = k & 7;
    int j = s_idx[e];
    float l = sh_self[h] + s_neigh[j * 8 + h];
    s_w[e][h] = l > 0.f ? l : ALPHA * l;
  }
  __syncthreads();

  // softmax stats: wave wid owns head wid
  {
    const int h = wid;
    float m = -1e30f;
    for (int e = lane; e < deg; e += 64) m = fmaxf(m, s_w[e][h]);
#pragma unroll
    for (int s = 32; s > 0; s >>= 1) m = fmaxf(m, __shfl_xor(m, s, 64));
    m = fmaxf(m, 0.0f);  // non-edge dense entries are exactly 0
    float e0 = __expf(-m);
    float zs = 0.f;
    for (int e = lane; e < deg; e += 64) {
      float w = __expf(s_w[e][h] - m);
      s_w[e][h] = w - e0;  // edge weight minus colsum-correction share
      zs += w;
    }
#pragma unroll
    for (int s = 32; s > 0; s >>= 1) zs += __shfl_xor(zs, s, 64);
    if (lane == 0) {
      sh_e0[h] = e0;
      sh_invZ[h] = 1.0f / (zs + (float)(N_NODES - deg) * e0);
    }
  }
  __syncthreads();

  // gather: cp = column pair, half = which edge range; 8 FMA chains each
  const int cp = tid & 255;
  const int half = tid >> 8;
  const int h = cp >> 5;
  const int dhalf = (deg + 1) >> 1;
  const int ebeg = half ? dhalf : 0;
  const int eend = half ? deg : dhalf;
  const ushort2* __restrict__ fb = reinterpret_cast<const ushort2*>(featsb);
  float ax0 = 0.f, ay0 = 0.f, ax1 = 0.f, ay1 = 0.f;
  float ax2 = 0.f, ay2 = 0.f, ax3 = 0.f, ay3 = 0.f;
  int e = ebeg;
  for (; e + 3 < eend; e += 4) {
    int j0 = s_idx[e], j1 = s_idx[e + 1], j2 = s_idx[e + 2], j3 = s_idx[e + 3];
    float w0 = s_w[e][h], w1 = s_w[e + 1][h];
    float w2 = s_w[e + 2][h], w3 = s_w[e + 3][h];
    ushort2 u0 = fb[(size_t)j0 * 256 + cp];
    ushort2 u1 = fb[(size_t)j1 * 256 + cp];
    ushort2 u2 = fb[(size_t)j2 * 256 + cp];
    ushort2 u3 = fb[(size_t)j3 * 256 + cp];
    ax0 = fmaf(w0, bf2f(u0.x), ax0);
    ay0 = fmaf(w0, bf2f(u0.y), ay0);
    ax1 = fmaf(w1, bf2f(u1.x), ax1);
    ay1 = fmaf(w1, bf2f(u1.y), ay1);
    ax2 = fmaf(w2, bf2f(u2.x), ax2);
    ay2 = fmaf(w2, bf2f(u2.y), ay2);
    ax3 = fmaf(w3, bf2f(u3.x), ax3);
    ay3 = fmaf(w3, bf2f(u3.y), ay3);
  }
  for (; e < eend; ++e) {
    float w0 = s_w[e][h];
    ushort2 u0 = fb[(size_t)s_idx[e] * 256 + cp];
    ax0 = fmaf(w0, bf2f(u0.x), ax0);
    ay0 = fmaf(w0, bf2f(u0.y), ay0);
  }
  float ax = (ax0 + ax1) + (ax2 + ax3);
  float ay = (ay0 + ay1) + (ay2 + ay3);
  if (half) {
    s_part[cp][0] = ax;
    s_part[cp][1] = ay;
  }
  __syncthreads();
  if (!half) {
    const float e0 = sh_e0[h], invZ = sh_invZ[h];
    const float2 cs = *reinterpret_cast<const float2*>(&colsum[cp * 2]);
    ax += s_part[cp][0] + e0 * cs.x;
    ay += s_part[cp][1] + e0 * cs.y;
    const float2 bb = *reinterpret_cast<const float2*>(&bias[cp * 2]);
    float vx = ax * invZ + bb.x;
    float vy = ay * invZ + bb.y;
    float2 o;
    o.x = vx > 0.f ? vx : 0.f;
    o.y = vy > 0.f ? vy : 0.f;
    *reinterpret_cast<float2*>(&out[(size_t)i * C_OUT + cp * 2]) = o;
  }
}

extern "C" void kernel_launch(void* const* d_in, const int* in_sizes, int n_in,
                              void* d_out, int out_size, void* d_ws, size_t ws_size,
                              hipStream_t stream) {
  const float* X = (const float*)d_in[0];
  const float* A = (const float*)d_in[1];
  const float* W = (const float*)d_in[2];
  const float* a_self = (const float*)d_in[3];
  const float* a_neigh = (const float*)d_in[4];
  const float* b = (const float*)d_in[5];
  float* out = (float*)d_out;

  char* ws = (char*)d_ws;
  unsigned short* featsb = (unsigned short*)ws;               // 4 MB
  char* p = ws + (size_t)N_NODES * C_OUT * 2;
  float* s_self = (float*)p;  p += N_NODES * H_HEADS * 4;     // 128 KB
  float* s_neigh = (float*)p; p += N_NODES * H_HEADS * 4;     // 128 KB
  float* colsum = (float*)p;  p += C_OUT * 4;                 // 2 KB
  int* degs = (int*)p;        p += N_NODES * 4;               // 16 KB
  unsigned short* edges = (unsigned short*)p;
  p += (size_t)N_NODES * MAXE * 2;                            // 1.5 MB
  unsigned short* WbT = (unsigned short*)p;                   // 512 KB

  // Xb parked in d_out (4 MB of its 8 MB); attn fully overwrites d_out later.
  unsigned short* Xb = (unsigned short*)d_out;

  stream_kernel<<<N_NODES + 2048 + 64 + 1, 256, 0, stream>>>(
      A, X, W, edges, degs, Xb, WbT, colsum);
  gemm_feats_mfma_kernel<<<dim3(64, 8), 256, 0, stream>>>(
      Xb, WbT, a_self, a_neigh, featsb, s_self, s_neigh, colsum);
  attn_kernel<<<N_NODES, 512, 0, stream>>>(edges, degs, featsb, s_self,
                                           s_neigh, colsum, b, out);
}

// Round 10
// 61.175 us; speedup vs baseline: 1.0524x; 1.0524x over previous
//
#include <hip/hip_runtime.h>
#include <hip/hip_bf16.h>

#define N_NODES 4096
#define F_IN 512
#define FHD 64
#define H_HEADS 8
#define C_OUT 512   /* H*FH */
#define ALPHA 0.2f
#define MAXE 192

typedef __attribute__((ext_vector_type(8))) short bf16x8;
typedef __attribute__((ext_vector_type(4))) float f32x4;

static __device__ __forceinline__ unsigned short f2bf(float f) {
  __hip_bfloat16 h = __float2bfloat16(f);
  union { __hip_bfloat16 h; unsigned short u; } cvt;
  cvt.h = h;
  return cvt.u;
}

// ---------------------------------------------------------------------------
// stream: all pure-streaming, mutually independent work in ONE launch.
// blocks [0,4096): A-row CSR scan | [4096,6144): X->bf16 | [6144,6208): W
// transpose->bf16 | 6208: zero colsum.
// ---------------------------------------------------------------------------
__global__ __launch_bounds__(256) void stream_kernel(
    const float* __restrict__ A, const float* __restrict__ X,
    const float* __restrict__ W, unsigned short* __restrict__ edges,
    int* __restrict__ degs, unsigned short* __restrict__ Xb,
    unsigned short* __restrict__ WbT, float* __restrict__ colsum) {
  __shared__ int wave_tot[4];
  __shared__ float sT[64][65];
  const int bid = blockIdx.x;
  const int tid = threadIdx.x;

  if (bid < N_NODES) {
    const int i = bid;
    const int wid = tid >> 6, lane = tid & 63;
    const float4* __restrict__ Arow4 =
        reinterpret_cast<const float4*>(A + (size_t)i * N_NODES);
    float4 v[4];
#pragma unroll
    for (int q = 0; q < 4; ++q) v[q] = Arow4[tid * 4 + q];
    int mask16 = 0;
#pragma unroll
    for (int q = 0; q < 4; ++q) {
      mask16 |= (v[q].x != 0.f) ? (1 << (q * 4 + 0)) : 0;
      mask16 |= (v[q].y != 0.f) ? (1 << (q * 4 + 1)) : 0;
      mask16 |= (v[q].z != 0.f) ? (1 << (q * 4 + 2)) : 0;
      mask16 |= (v[q].w != 0.f) ? (1 << (q * 4 + 3)) : 0;
    }
    int cnt = __popc(mask16);
    int inc = cnt;
#pragma unroll
    for (int s = 1; s < 64; s <<= 1) {
      int t = __shfl_up(inc, s, 64);
      if (lane >= s) inc += t;
    }
    if (lane == 63) wave_tot[wid] = inc;
    __syncthreads();
    int wprefix = 0, tot = 0;
#pragma unroll
    for (int w = 0; w < 4; ++w) {
      int t = wave_tot[w];
      if (w < wid) wprefix += t;
      tot += t;
    }
    int pos = wprefix + inc - cnt;
    const int jbase = tid * 16;
    unsigned short* __restrict__ erow = edges + (size_t)i * MAXE;
    while (mask16) {
      int k = __ffs(mask16) - 1;
      mask16 &= mask16 - 1;
      if (pos < MAXE) erow[pos] = (unsigned short)(jbase + k);
      ++pos;
    }
    if (tid == 0) degs[i] = tot < MAXE ? tot : MAXE;
  } else if (bid < N_NODES + 2048) {
    int idx = (bid - N_NODES) * 256 + tid;
    float4 v = reinterpret_cast<const float4*>(X)[idx];
    ushort4 u;
    u.x = f2bf(v.x); u.y = f2bf(v.y); u.z = f2bf(v.z); u.w = f2bf(v.w);
    reinterpret_cast<ushort4*>(Xb)[idx] = u;
  } else if (bid < N_NODES + 2048 + 64) {
    const int b2 = bid - (N_NODES + 2048);
    const int fblk = b2 & 7, h = b2 >> 3;
#pragma unroll
    for (int i = 0; i < 16; ++i) {
      int idx = tid + i * 256;
      int f = idx >> 6, o = idx & 63;
      sT[f][o] = W[((size_t)h * F_IN + fblk * 64 + f) * FHD + o];
    }
    __syncthreads();
#pragma unroll
    for (int i = 0; i < 16; ++i) {
      int idx = tid + i * 256;
      int o = idx >> 6, f = idx & 63;
      WbT[(size_t)h * FHD * F_IN + (size_t)o * F_IN + fblk * 64 + f] =
          f2bf(sT[f][o]);
    }
  } else {
    colsum[tid] = 0.f;
    colsum[tid + 256] = 0.f;
  }
}

// ---------------------------------------------------------------------------
// MFMA GEMM: 64 rows x 1 head per block, BK=64, grid (64,8)=512 blocks.
// Fused: s_self/s_neigh scores + colsum partials (atomicAdd).
// ---------------------------------------------------------------------------
__global__ __launch_bounds__(256) void gemm_feats_mfma_kernel(
    const unsigned short* __restrict__ Xb, const unsigned short* __restrict__ WbT,
    const float* __restrict__ a_self, const float* __restrict__ a_neigh,
    unsigned short* __restrict__ featsb,
    float* __restrict__ s_self, float* __restrict__ s_neigh,
    float* __restrict__ colsum) {
  const int h = blockIdx.y;
  const int n0 = blockIdx.x * 64;
  __shared__ unsigned short sX[2][64 * 72];
  __shared__ unsigned short sW[2][64 * 72];
  __shared__ float sred[4][64];
  const int tid = threadIdx.x;
  const int wid = tid >> 6, lane = tid & 63;
  const int l15 = lane & 15, l4 = lane >> 4;

  const int row = tid >> 2, seg = (tid & 3) * 16;
  const unsigned short* xsrc = Xb + (size_t)(n0 + row) * F_IN + seg;
  const unsigned short* wsrc = WbT + ((size_t)h * FHD + row) * F_IN + seg;
  const int soff = row * 72 + seg;

  f32x4 acc[4];
#pragma unroll
  for (int j = 0; j < 4; ++j) acc[j] = (f32x4){0.f, 0.f, 0.f, 0.f};

  *(bf16x8*)&sX[0][soff] = *(const bf16x8*)(xsrc);
  *(bf16x8*)&sX[0][soff + 8] = *(const bf16x8*)(xsrc + 8);
  *(bf16x8*)&sW[0][soff] = *(const bf16x8*)(wsrc);
  *(bf16x8*)&sW[0][soff + 8] = *(const bf16x8*)(wsrc + 8);
  __syncthreads();

  int cur = 0;
  for (int s = 0; s < 8; ++s) {
    bf16x8 px0, px1, pw0, pw1;
    const bool pf = (s < 7);
    if (pf) {
      const int k = (s + 1) * 64;
      px0 = *(const bf16x8*)(xsrc + k);
      px1 = *(const bf16x8*)(xsrc + k + 8);
      pw0 = *(const bf16x8*)(wsrc + k);
      pw1 = *(const bf16x8*)(wsrc + k + 8);
    }
#pragma unroll
    for (int kk = 0; kk < 2; ++kk) {
      bf16x8 a = *(const bf16x8*)&sX[cur][(wid * 16 + l15) * 72 + kk * 32 + l4 * 8];
#pragma unroll
      for (int tn = 0; tn < 4; ++tn) {
        bf16x8 b = *(const bf16x8*)&sW[cur][(tn * 16 + l15) * 72 + kk * 32 + l4 * 8];
        acc[tn] =
            __builtin_amdgcn_mfma_f32_16x16x32_bf16(a, b, acc[tn], 0, 0, 0);
      }
    }
    if (pf) {
      *(bf16x8*)&sX[cur ^ 1][soff] = px0;
      *(bf16x8*)&sX[cur ^ 1][soff + 8] = px1;
      *(bf16x8*)&sW[cur ^ 1][soff] = pw0;
      *(bf16x8*)&sW[cur ^ 1][soff + 8] = pw1;
      __syncthreads();
      cur ^= 1;
    }
  }

  float aS[4], aN[4];
#pragma unroll
  for (int tn = 0; tn < 4; ++tn) {
    aS[tn] = a_self[h * FHD + tn * 16 + l15];
    aN[tn] = a_neigh[h * FHD + tn * 16 + l15];
  }
#pragma unroll
  for (int r = 0; r < 4; ++r) {
    const int grow = n0 + wid * 16 + l4 * 4 + r;
#pragma unroll
    for (int tn = 0; tn < 4; ++tn)
      featsb[(size_t)grow * C_OUT + h * FHD + tn * 16 + l15] =
          f2bf(acc[tn][r]);
    float ps = 0.f, pn = 0.f;
#pragma unroll
    for (int tn = 0; tn < 4; ++tn) {
      float v = acc[tn][r];
      ps = fmaf(v, aS[tn], ps);
      pn = fmaf(v, aN[tn], pn);
    }
#pragma unroll
    for (int sh = 1; sh < 16; sh <<= 1) {
      ps += __shfl_xor(ps, sh, 64);
      pn += __shfl_xor(pn, sh, 64);
    }
    if (l15 == 0) {
      s_self[grow * 8 + h] = ps;
      s_neigh[grow * 8 + h] = pn;
    }
  }

  float psum[4];
#pragma unroll
  for (int tn = 0; tn < 4; ++tn) {
    float s = acc[tn][0] + acc[tn][1] + acc[tn][2] + acc[tn][3];
    s += __shfl_xor(s, 16, 64);
    s += __shfl_xor(s, 32, 64);
    psum[tn] = s;
  }
  if (l4 == 0) {
#pragma unroll
    for (int tn = 0; tn < 4; ++tn) sred[wid][tn * 16 + l15] = psum[tn];
  }
  __syncthreads();
  if (tid < 64) {
    float s = sred[0][tid] + sred[1][tid] + sred[2][tid] + sred[3][tid];
    atomicAdd(&colsum[h * FHD + tid], s);
  }
}

// ---------------------------------------------------------------------------
// attn v3: 256 threads/block (8 blocks/CU for TLP), one block per row i.
// s_iw[e][h] = {j*1024 byte-offset, weight} -> gather inner loop is one
// ds_read_b64 + one 8B global load + 4 unpack + 4 FMA per 4 columns.
// 128 col-quad threads x 2 edge halves; combine via LDS.
// ---------------------------------------------------------------------------
__global__ __launch_bounds__(256) void attn_kernel(
    const unsigned short* __restrict__ edges, const int* __restrict__ degs,
    const unsigned short* __restrict__ featsb,
    const float* __restrict__ s_self, const float* __restrict__ s_neigh,
    const float* __restrict__ colsum, const float* __restrict__ bias,
    float* __restrict__ out) {
  const int i = blockIdx.x;
  const int tid = threadIdx.x;
  const int wid = tid >> 6, lane = tid & 63;
  __shared__ int s_idx[MAXE];
  __shared__ uint2 s_iw[MAXE][8];  // .x = j*1024 (byte off), .y = f32 bits
  __shared__ float sh_self[8];
  __shared__ float sh_e0[8], sh_invZ[8];
  __shared__ float s_part[128][4];

  const int deg = degs[i];
  if (tid < 8) sh_self[tid] = s_self[i * 8 + tid];
  if (tid < deg) s_idx[tid] = edges[(size_t)i * MAXE + tid];
  __syncthreads();

  // Phase 1: logits into s_iw[e][h].y; byte offset into .x
  for (int k = tid; k < deg * 8; k += 256) {
    int e = k >> 3, h = k & 7;
    int j = s_idx[e];
    float l = sh_self[h] + s_neigh[j * 8 + h];
    l = l > 0.f ? l : ALPHA * l;
    s_iw[e][h] = make_uint2((unsigned)(j << 10), __float_as_uint(l));
  }
  __syncthreads();

  // Phase 2: per-head softmax stats; wave wid owns heads 2wid, 2wid+1
#pragma unroll
  for (int p = 0; p < 2; ++p) {
    const int h = wid * 2 + p;
    float m = -1e30f;
    for (int e = lane; e < deg; e += 64)
      m = fmaxf(m, __uint_as_float(s_iw[e][h].y));
#pragma unroll
    for (int s = 32; s > 0; s >>= 1) m = fmaxf(m, __shfl_xor(m, s, 64));
    m = fmaxf(m, 0.0f);  // non-edge dense entries are exactly 0
    float e0 = __expf(-m);
    float zs = 0.f;
    for (int e = lane; e < deg; e += 64) {
      float w = __expf(__uint_as_float(s_iw[e][h].y) - m);
      s_iw[e][h].y = __float_as_uint(w - e0);  // minus colsum-correction share
      zs += w;
    }
#pragma unroll
    for (int s = 32; s > 0; s >>= 1) zs += __shfl_xor(zs, s, 64);
    if (lane == 0) {
      sh_e0[h] = e0;
      sh_invZ[h] = 1.0f / (zs + (float)(N_NODES - deg) * e0);
    }
  }
  __syncthreads();

  // Phase 3: gather. cq = column quad (4 cols), half = edge range.
  const int cq = tid & 127;
  const int half = tid >> 7;
  const int h = cq >> 4;
  const int dhalf = (deg + 1) >> 1;
  const int ebeg = half ? dhalf : 0;
  const int eend = half ? deg : dhalf;
  const char* __restrict__ fbase =
      reinterpret_cast<const char*>(featsb) + cq * 8;
  float a0 = 0.f, a1 = 0.f, a2 = 0.f, a3 = 0.f;
  float b0 = 0.f, b1 = 0.f, b2 = 0.f, b3 = 0.f;
  int e = ebeg;
  for (; e + 1 < eend; e += 2) {
    uint2 jw0 = s_iw[e][h];
    uint2 jw1 = s_iw[e + 1][h];
    float w0 = __uint_as_float(jw0.y);
    float w1 = __uint_as_float(jw1.y);
    uint2 u0 = *reinterpret_cast<const uint2*>(fbase + jw0.x);
    uint2 u1 = *reinterpret_cast<const uint2*>(fbase + jw1.x);
    a0 = fmaf(w0, __uint_as_float(u0.x << 16), a0);
    a1 = fmaf(w0, __uint_as_float(u0.x & 0xFFFF0000u), a1);
    a2 = fmaf(w0, __uint_as_float(u0.y << 16), a2);
    a3 = fmaf(w0, __uint_as_float(u0.y & 0xFFFF0000u), a3);
    b0 = fmaf(w1, __uint_as_float(u1.x << 16), b0);
    b1 = fmaf(w1, __uint_as_float(u1.x & 0xFFFF0000u), b1);
    b2 = fmaf(w1, __uint_as_float(u1.y << 16), b2);
    b3 = fmaf(w1, __uint_as_float(u1.y & 0xFFFF0000u), b3);
  }
  if (e < eend) {
    uint2 jw0 = s_iw[e][h];
    float w0 = __uint_as_float(jw0.y);
    uint2 u0 = *reinterpret_cast<const uint2*>(fbase + jw0.x);
    a0 = fmaf(w0, __uint_as_float(u0.x << 16), a0);
    a1 = fmaf(w0, __uint_as_float(u0.x & 0xFFFF0000u), a1);
    a2 = fmaf(w0, __uint_as_float(u0.y << 16), a2);
    a3 = fmaf(w0, __uint_as_float(u0.y & 0xFFFF0000u), a3);
  }
  a0 += b0; a1 += b1; a2 += b2; a3 += b3;
  if (half) {
    s_part[cq][0] = a0;
    s_part[cq][1] = a1;
    s_part[cq][2] = a2;
    s_part[cq][3] = a3;
  }
  __syncthreads();
  if (!half) {
    const float e0 = sh_e0[h], invZ = sh_invZ[h];
    const float4 cs = *reinterpret_cast<const float4*>(&colsum[cq * 4]);
    const float4 bb = *reinterpret_cast<const float4*>(&bias[cq * 4]);
    float v0 = (a0 + s_part[cq][0] + e0 * cs.x) * invZ + bb.x;
    float v1 = (a1 + s_part[cq][1] + e0 * cs.y) * invZ + bb.y;
    float v2 = (a2 + s_part[cq][2] + e0 * cs.z) * invZ + bb.z;
    float v3 = (a3 + s_part[cq][3] + e0 * cs.w) * invZ + bb.w;
    float4 o;
    o.x = v0 > 0.f ? v0 : 0.f;
    o.y = v1 > 0.f ? v1 : 0.f;
    o.z = v2 > 0.f ? v2 : 0.f;
    o.w = v3 > 0.f ? v3 : 0.f;
    *reinterpret_cast<float4*>(&out[(size_t)i * C_OUT + cq * 4]) = o;
  }
}

extern "C" void kernel_launch(void* const* d_in, const int* in_sizes, int n_in,
                              void* d_out, int out_size, void* d_ws, size_t ws_size,
                              hipStream_t stream) {
  const float* X = (const float*)d_in[0];
  const float* A = (const float*)d_in[1];
  const float* W = (const float*)d_in[2];
  const float* a_self = (const float*)d_in[3];
  const float* a_neigh = (const float*)d_in[4];
  const float* b = (const float*)d_in[5];
  float* out = (float*)d_out;

  char* ws = (char*)d_ws;
  unsigned short* featsb = (unsigned short*)ws;               // 4 MB
  char* p = ws + (size_t)N_NODES * C_OUT * 2;
  float* s_self = (float*)p;  p += N_NODES * H_HEADS * 4;     // 128 KB
  float* s_neigh = (float*)p; p += N_NODES * H_HEADS * 4;     // 128 KB
  float* colsum = (float*)p;  p += C_OUT * 4;                 // 2 KB
  int* degs = (int*)p;        p += N_NODES * 4;               // 16 KB
  unsigned short* edges = (unsigned short*)p;
  p += (size_t)N_NODES * MAXE * 2;                            // 1.5 MB
  unsigned short* WbT = (unsigned short*)p;                   // 512 KB

  // Xb parked in d_out (4 MB of its 8 MB); attn fully overwrites d_out later.
  unsigned short* Xb = (unsigned short*)d_out;

  stream_kernel<<<N_NODES + 2048 + 64 + 1, 256, 0, stream>>>(
      A, X, W, edges, degs, Xb, WbT, colsum);
  gemm_feats_mfma_kernel<<<dim3(64, 8), 256, 0, stream>>>(
      Xb, WbT, a_self, a_neigh, featsb, s_self, s_neigh, colsum);
  attn_kernel<<<N_NODES, 256, 0, stream>>>(edges, degs, featsb, s_self,
                                           s_neigh, colsum, b, out);
}

// Round 11
// 57.768 us; speedup vs baseline: 1.1145x; 1.0590x over previous
//
#include <hip/hip_runtime.h>
#include <hip/hip_bf16.h>

#define N_NODES 4096
#define F_IN 512
#define FHD 64
#define H_HEADS 8
#define C_OUT 512   /* H*FH */
#define ALPHA 0.2f
#define MAXE 192
#define MAXE_P 200  /* head-major weight row stride: (h*200)%32 = h*8 -> conflict-free */
#define GEMM_BLOCKS 512

typedef __attribute__((ext_vector_type(8))) short bf16x8;
typedef __attribute__((ext_vector_type(4))) float f32x4;

static __device__ __forceinline__ unsigned short f2bf(float f) {
  __hip_bfloat16 h = __float2bfloat16(f);
  union { __hip_bfloat16 h; unsigned short u; } cvt;
  cvt.h = h;
  return cvt.u;
}

// ---------------------------------------------------------------------------
// conv: blocks [0,2048) X->bf16 | [2048,2112) W transpose->bf16 | 2112 zero
// colsum.
// ---------------------------------------------------------------------------
__global__ __launch_bounds__(256) void conv_kernel(
    const float* __restrict__ X, const float* __restrict__ W,
    unsigned short* __restrict__ Xb, unsigned short* __restrict__ WbT,
    float* __restrict__ colsum) {
  __shared__ float sT[64][65];
  const int bid = blockIdx.x;
  const int tid = threadIdx.x;
  if (bid < 2048) {
    int idx = bid * 256 + tid;
    float4 v = reinterpret_cast<const float4*>(X)[idx];
    ushort4 u;
    u.x = f2bf(v.x); u.y = f2bf(v.y); u.z = f2bf(v.z); u.w = f2bf(v.w);
    reinterpret_cast<ushort4*>(Xb)[idx] = u;
  } else if (bid < 2048 + 64) {
    const int b2 = bid - 2048;
    const int fblk = b2 & 7, h = b2 >> 3;
#pragma unroll
    for (int i = 0; i < 16; ++i) {
      int idx = tid + i * 256;
      int f = idx >> 6, o = idx & 63;
      sT[f][o] = W[((size_t)h * F_IN + fblk * 64 + f) * FHD + o];
    }
    __syncthreads();
#pragma unroll
    for (int i = 0; i < 16; ++i) {
      int idx = tid + i * 256;
      int o = idx >> 6, f = idx & 63;
      WbT[(size_t)h * FHD * F_IN + (size_t)o * F_IN + fblk * 64 + f] =
          f2bf(sT[f][o]);
    }
  } else {
    colsum[tid] = 0.f;
    colsum[tid + 256] = 0.f;
  }
}

// ---------------------------------------------------------------------------
// gemm_scan: blocks [0,512) MFMA GEMM (64 rows x 1 head, BK=64, dbuf);
// blocks [512,4608) A-row CSR scan. Co-resident: scan's HBM stream overlaps
// the GEMM's MFMA/LDS phases (R8-proven).
// ---------------------------------------------------------------------------
__global__ __launch_bounds__(256) void gemm_scan_kernel(
    const unsigned short* __restrict__ Xb, const unsigned short* __restrict__ WbT,
    const float* __restrict__ a_self, const float* __restrict__ a_neigh,
    const float* __restrict__ A,
    unsigned short* __restrict__ featsb,
    float* __restrict__ s_self, float* __restrict__ s_neigh,
    float* __restrict__ colsum,
    unsigned short* __restrict__ edges, int* __restrict__ degs) {
  __shared__ unsigned short sX[2][64 * 72];
  __shared__ unsigned short sW[2][64 * 72];
  __shared__ float sred[4][64];
  const int bid = blockIdx.x;
  const int tid = threadIdx.x;
  const int wid = tid >> 6, lane = tid & 63;

  if (bid >= GEMM_BLOCKS) {
    // ---- scan path: CSR build for row i
    const int i = bid - GEMM_BLOCKS;
    int* wave_tot = reinterpret_cast<int*>(&sred[0][0]);
    const float4* __restrict__ Arow4 =
        reinterpret_cast<const float4*>(A + (size_t)i * N_NODES);
    float4 v[4];
#pragma unroll
    for (int q = 0; q < 4; ++q) v[q] = Arow4[tid * 4 + q];
    int mask16 = 0;
#pragma unroll
    for (int q = 0; q < 4; ++q) {
      mask16 |= (v[q].x != 0.f) ? (1 << (q * 4 + 0)) : 0;
      mask16 |= (v[q].y != 0.f) ? (1 << (q * 4 + 1)) : 0;
      mask16 |= (v[q].z != 0.f) ? (1 << (q * 4 + 2)) : 0;
      mask16 |= (v[q].w != 0.f) ? (1 << (q * 4 + 3)) : 0;
    }
    int cnt = __popc(mask16);
    int inc = cnt;
#pragma unroll
    for (int s = 1; s < 64; s <<= 1) {
      int t = __shfl_up(inc, s, 64);
      if (lane >= s) inc += t;
    }
    if (lane == 63) wave_tot[wid] = inc;
    __syncthreads();
    int wprefix = 0, tot = 0;
#pragma unroll
    for (int w = 0; w < 4; ++w) {
      int t = wave_tot[w];
      if (w < wid) wprefix += t;
      tot += t;
    }
    int pos = wprefix + inc - cnt;
    const int jbase = tid * 16;
    unsigned short* __restrict__ erow = edges + (size_t)i * MAXE;
    while (mask16) {
      int k = __ffs(mask16) - 1;
      mask16 &= mask16 - 1;
      if (pos < MAXE) erow[pos] = (unsigned short)(jbase + k);
      ++pos;
    }
    if (tid == 0) degs[i] = tot < MAXE ? tot : MAXE;
    return;
  }

  // ---- GEMM path
  const int h = bid >> 6;
  const int n0 = (bid & 63) * 64;
  const int l15 = lane & 15, l4 = lane >> 4;

  const int row = tid >> 2, seg = (tid & 3) * 16;
  const unsigned short* xsrc = Xb + (size_t)(n0 + row) * F_IN + seg;
  const unsigned short* wsrc = WbT + ((size_t)h * FHD + row) * F_IN + seg;
  const int soff = row * 72 + seg;

  f32x4 acc[4];
#pragma unroll
  for (int j = 0; j < 4; ++j) acc[j] = (f32x4){0.f, 0.f, 0.f, 0.f};

  *(bf16x8*)&sX[0][soff] = *(const bf16x8*)(xsrc);
  *(bf16x8*)&sX[0][soff + 8] = *(const bf16x8*)(xsrc + 8);
  *(bf16x8*)&sW[0][soff] = *(const bf16x8*)(wsrc);
  *(bf16x8*)&sW[0][soff + 8] = *(const bf16x8*)(wsrc + 8);
  __syncthreads();

  int cur = 0;
  for (int s = 0; s < 8; ++s) {
    bf16x8 px0, px1, pw0, pw1;
    const bool pf = (s < 7);
    if (pf) {
      const int k = (s + 1) * 64;
      px0 = *(const bf16x8*)(xsrc + k);
      px1 = *(const bf16x8*)(xsrc + k + 8);
      pw0 = *(const bf16x8*)(wsrc + k);
      pw1 = *(const bf16x8*)(wsrc + k + 8);
    }
#pragma unroll
    for (int kk = 0; kk < 2; ++kk) {
      bf16x8 a = *(const bf16x8*)&sX[cur][(wid * 16 + l15) * 72 + kk * 32 + l4 * 8];
#pragma unroll
      for (int tn = 0; tn < 4; ++tn) {
        bf16x8 b = *(const bf16x8*)&sW[cur][(tn * 16 + l15) * 72 + kk * 32 + l4 * 8];
        acc[tn] =
            __builtin_amdgcn_mfma_f32_16x16x32_bf16(a, b, acc[tn], 0, 0, 0);
      }
    }
    if (pf) {
      *(bf16x8*)&sX[cur ^ 1][soff] = px0;
      *(bf16x8*)&sX[cur ^ 1][soff + 8] = px1;
      *(bf16x8*)&sW[cur ^ 1][soff] = pw0;
      *(bf16x8*)&sW[cur ^ 1][soff + 8] = pw1;
      __syncthreads();
      cur ^= 1;
    }
  }

  float aS[4], aN[4];
#pragma unroll
  for (int tn = 0; tn < 4; ++tn) {
    aS[tn] = a_self[h * FHD + tn * 16 + l15];
    aN[tn] = a_neigh[h * FHD + tn * 16 + l15];
  }
#pragma unroll
  for (int r = 0; r < 4; ++r) {
    const int grow = n0 + wid * 16 + l4 * 4 + r;
#pragma unroll
    for (int tn = 0; tn < 4; ++tn)
      featsb[(size_t)grow * C_OUT + h * FHD + tn * 16 + l15] =
          f2bf(acc[tn][r]);
    float ps = 0.f, pn = 0.f;
#pragma unroll
    for (int tn = 0; tn < 4; ++tn) {
      float v = acc[tn][r];
      ps = fmaf(v, aS[tn], ps);
      pn = fmaf(v, aN[tn], pn);
    }
#pragma unroll
    for (int sh = 1; sh < 16; sh <<= 1) {
      ps += __shfl_xor(ps, sh, 64);
      pn += __shfl_xor(pn, sh, 64);
    }
    if (l15 == 0) {
      s_self[grow * 8 + h] = ps;
      s_neigh[grow * 8 + h] = pn;
    }
  }

  float psum[4];
#pragma unroll
  for (int tn = 0; tn < 4; ++tn) {
    float s = acc[tn][0] + acc[tn][1] + acc[tn][2] + acc[tn][3];
    s += __shfl_xor(s, 16, 64);
    s += __shfl_xor(s, 32, 64);
    psum[tn] = s;
  }
  __syncthreads();  // sred aliased by scan path layout; order with MFMA loop
  if (l4 == 0) {
#pragma unroll
    for (int tn = 0; tn < 4; ++tn) sred[wid][tn * 16 + l15] = psum[tn];
  }
  __syncthreads();
  if (tid < 64) {
    float s = sred[0][tid] + sred[1][tid] + sred[2][tid] + sred[3][tid];
    atomicAdd(&colsum[h * FHD + tid], s);
  }
}

// ---------------------------------------------------------------------------
// attn v4: 256 threads/block (8 blocks/CU), one block per row i.
// Bank-exact LDS: s_idx/s_off reads are wave-uniform (broadcast); weights
// head-major s_w[8][200] -> phase-2 stride-1, phase-3 rows on distinct banks.
// Gather: 128 col-quad threads x 2 edge halves; 4 cols = one 8B load.
// ---------------------------------------------------------------------------
__global__ __launch_bounds__(256) void attn_kernel(
    const unsigned short* __restrict__ edges, const int* __restrict__ degs,
    const unsigned short* __restrict__ featsb,
    const float* __restrict__ s_self, const float* __restrict__ s_neigh,
    const float* __restrict__ colsum, const float* __restrict__ bias,
    float* __restrict__ out) {
  const int i = blockIdx.x;
  const int tid = threadIdx.x;
  const int wid = tid >> 6, lane = tid & 63;
  __shared__ int s_idx[MAXE];
  __shared__ int s_off[MAXE];          // j*1024 byte offsets
  __shared__ float s_w[H_HEADS][MAXE_P];
  __shared__ float sh_self[8];
  __shared__ float sh_e0[8], sh_invZ[8];
  __shared__ float s_part[128][4];

  const int deg = degs[i];
  if (tid < 8) sh_self[tid] = s_self[i * 8 + tid];
  if (tid < deg) {
    int j = edges[(size_t)i * MAXE + tid];
    s_idx[tid] = j;
    s_off[tid] = j << 10;
  }
  __syncthreads();

  // Phase 1: logits, head-major
  for (int k = tid; k < deg * 8; k += 256) {
    int e = k >> 3, h = k & 7;
    int j = s_idx[e];
    float l = sh_self[h] + s_neigh[j * 8 + h];
    s_w[h][e] = l > 0.f ? l : ALPHA * l;
  }
  __syncthreads();

  // Phase 2: per-head softmax stats; wave wid owns heads 2wid, 2wid+1
#pragma unroll
  for (int p = 0; p < 2; ++p) {
    const int h = wid * 2 + p;
    float m = -1e30f;
    for (int e = lane; e < deg; e += 64) m = fmaxf(m, s_w[h][e]);
#pragma unroll
    for (int s = 32; s > 0; s >>= 1) m = fmaxf(m, __shfl_xor(m, s, 64));
    m = fmaxf(m, 0.0f);  // non-edge dense entries are exactly 0
    float e0 = __expf(-m);
    float zs = 0.f;
    for (int e = lane; e < deg; e += 64) {
      float w = __expf(s_w[h][e] - m);
      s_w[h][e] = w - e0;  // minus colsum-correction share
      zs += w;
    }
#pragma unroll
    for (int s = 32; s > 0; s >>= 1) zs += __shfl_xor(zs, s, 64);
    if (lane == 0) {
      sh_e0[h] = e0;
      sh_invZ[h] = 1.0f / (zs + (float)(N_NODES - deg) * e0);
    }
  }
  __syncthreads();

  // Phase 3: gather. cq = column quad (4 cols), half = edge range.
  const int cq = tid & 127;
  const int half = tid >> 7;
  const int h = cq >> 4;
  const int dhalf = (deg + 1) >> 1;
  const int ebeg = half ? dhalf : 0;
  const int eend = half ? deg : dhalf;
  const char* __restrict__ fbase =
      reinterpret_cast<const char*>(featsb) + cq * 8;
  float a0 = 0.f, a1 = 0.f, a2 = 0.f, a3 = 0.f;
  float b0 = 0.f, b1 = 0.f, b2 = 0.f, b3 = 0.f;
  int e = ebeg;
  for (; e + 1 < eend; e += 2) {
    float w0 = s_w[h][e];
    float w1 = s_w[h][e + 1];
    int o0 = s_off[e], o1 = s_off[e + 1];
    uint2 u0 = *reinterpret_cast<const uint2*>(fbase + o0);
    uint2 u1 = *reinterpret_cast<const uint2*>(fbase + o1);
    a0 = fmaf(w0, __uint_as_float(u0.x << 16), a0);
    a1 = fmaf(w0, __uint_as_float(u0.x & 0xFFFF0000u), a1);
    a2 = fmaf(w0, __uint_as_float(u0.y << 16), a2);
    a3 = fmaf(w0, __uint_as_float(u0.y & 0xFFFF0000u), a3);
    b0 = fmaf(w1, __uint_as_float(u1.x << 16), b0);
    b1 = fmaf(w1, __uint_as_float(u1.x & 0xFFFF0000u), b1);
    b2 = fmaf(w1, __uint_as_float(u1.y << 16), b2);
    b3 = fmaf(w1, __uint_as_float(u1.y & 0xFFFF0000u), b3);
  }
  if (e < eend) {
    float w0 = s_w[h][e];
    uint2 u0 = *reinterpret_cast<const uint2*>(fbase + s_off[e]);
    a0 = fmaf(w0, __uint_as_float(u0.x << 16), a0);
    a1 = fmaf(w0, __uint_as_float(u0.x & 0xFFFF0000u), a1);
    a2 = fmaf(w0, __uint_as_float(u0.y << 16), a2);
    a3 = fmaf(w0, __uint_as_float(u0.y & 0xFFFF0000u), a3);
  }
  a0 += b0; a1 += b1; a2 += b2; a3 += b3;
  if (half) {
    s_part[cq][0] = a0;
    s_part[cq][1] = a1;
    s_part[cq][2] = a2;
    s_part[cq][3] = a3;
  }
  __syncthreads();
  if (!half) {
    const float e0 = sh_e0[h], invZ = sh_invZ[h];
    const float4 cs = *reinterpret_cast<const float4*>(&colsum[cq * 4]);
    const float4 bb = *reinterpret_cast<const float4*>(&bias[cq * 4]);
    float v0 = (a0 + s_part[cq][0] + e0 * cs.x) * invZ + bb.x;
    float v1 = (a1 + s_part[cq][1] + e0 * cs.y) * invZ + bb.y;
    float v2 = (a2 + s_part[cq][2] + e0 * cs.z) * invZ + bb.z;
    float v3 = (a3 + s_part[cq][3] + e0 * cs.w) * invZ + bb.w;
    float4 o;
    o.x = v0 > 0.f ? v0 : 0.f;
    o.y = v1 > 0.f ? v1 : 0.f;
    o.z = v2 > 0.f ? v2 : 0.f;
    o.w = v3 > 0.f ? v3 : 0.f;
    *reinterpret_cast<float4*>(&out[(size_t)i * C_OUT + cq * 4]) = o;
  }
}

extern "C" void kernel_launch(void* const* d_in, const int* in_sizes, int n_in,
                              void* d_out, int out_size, void* d_ws, size_t ws_size,
                              hipStream_t stream) {
  const float* X = (const float*)d_in[0];
  const float* A = (const float*)d_in[1];
  const float* W = (const float*)d_in[2];
  const float* a_self = (const float*)d_in[3];
  const float* a_neigh = (const float*)d_in[4];
  const float* b = (const float*)d_in[5];
  float* out = (float*)d_out;

  char* ws = (char*)d_ws;
  unsigned short* featsb = (unsigned short*)ws;               // 4 MB
  char* p = ws + (size_t)N_NODES * C_OUT * 2;
  float* s_self = (float*)p;  p += N_NODES * H_HEADS * 4;     // 128 KB
  float* s_neigh = (float*)p; p += N_NODES * H_HEADS * 4;     // 128 KB
  float* colsum = (float*)p;  p += C_OUT * 4;                 // 2 KB
  int* degs = (int*)p;        p += N_NODES * 4;               // 16 KB
  unsigned short* edges = (unsigned short*)p;
  p += (size_t)N_NODES * MAXE * 2;                            // 1.5 MB
  unsigned short* WbT = (unsigned short*)p;                   // 512 KB

  // Xb parked in d_out (4 MB of its 8 MB); attn fully overwrites d_out later.
  unsigned short* Xb = (unsigned short*)d_out;

  conv_kernel<<<2048 + 64 + 1, 256, 0, stream>>>(X, W, Xb, WbT, colsum);
  gemm_scan_kernel<<<GEMM_BLOCKS + N_NODES, 256, 0, stream>>>(
      Xb, WbT, a_self, a_neigh, A, featsb, s_self, s_neigh, colsum, edges,
      degs);
  attn_kernel<<<N_NODES, 256, 0, stream>>>(edges, degs, featsb, s_self,
                                           s_neigh, colsum, b, out);
}

// Round 13
// 51.747 us; speedup vs baseline: 1.2442x; 1.1164x over previous
//
#include <hip/hip_runtime.h>
#include <hip/hip_bf16.h>

#define N_NODES 4096
#define F_IN 512
#define FHD 64
#define H_HEADS 8
#define C_OUT 512   /* H*FH */
#define ALPHA 0.2f
#define MAXE 192
#define MAXE_P 200  /* head-major weight row stride: (h*200)%32 = h*8 -> conflict-free */
#define GEMM_BLOCKS 512

typedef __attribute__((ext_vector_type(8))) short bf16x8;
typedef __attribute__((ext_vector_type(4))) float f32x4;

static __device__ __forceinline__ unsigned short f2bf(float f) {
  __hip_bfloat16 h = __float2bfloat16(f);
  union { __hip_bfloat16 h; unsigned short u; } cvt;
  cvt.h = h;
  return cvt.u;
}

// ---------------------------------------------------------------------------
// conv: blocks [0,2048) X->bf16 | [2048,2112) W transpose->bf16 | 2112 zero
// colsum.
// ---------------------------------------------------------------------------
__global__ __launch_bounds__(256) void conv_kernel(
    const float* __restrict__ X, const float* __restrict__ W,
    unsigned short* __restrict__ Xb, unsigned short* __restrict__ WbT,
    float* __restrict__ colsum) {
  __shared__ float sT[64][65];
  const int bid = blockIdx.x;
  const int tid = threadIdx.x;
  if (bid < 2048) {
    int idx = bid * 256 + tid;
    float4 v = reinterpret_cast<const float4*>(X)[idx];
    ushort4 u;
    u.x = f2bf(v.x); u.y = f2bf(v.y); u.z = f2bf(v.z); u.w = f2bf(v.w);
    reinterpret_cast<ushort4*>(Xb)[idx] = u;
  } else if (bid < 2048 + 64) {
    const int b2 = bid - 2048;
    const int fblk = b2 & 7, h = b2 >> 3;
#pragma unroll
    for (int i = 0; i < 16; ++i) {
      int idx = tid + i * 256;
      int f = idx >> 6, o = idx & 63;
      sT[f][o] = W[((size_t)h * F_IN + fblk * 64 + f) * FHD + o];
    }
    __syncthreads();
#pragma unroll
    for (int i = 0; i < 16; ++i) {
      int idx = tid + i * 256;
      int o = idx >> 6, f = idx & 63;
      WbT[(size_t)h * FHD * F_IN + (size_t)o * F_IN + fblk * 64 + f] =
          f2bf(sT[f][o]);
    }
  } else {
    colsum[tid] = 0.f;
    colsum[tid + 256] = 0.f;
  }
}

// ---------------------------------------------------------------------------
// gemm_scan: blocks [0,512) MFMA GEMM (64 rows x 1 head, BK=64, dbuf);
// blocks [512,4608) A-row CSR scan. Co-resident (R8-proven overlap).
// ---------------------------------------------------------------------------
__global__ __launch_bounds__(256) void gemm_scan_kernel(
    const unsigned short* __restrict__ Xb, const unsigned short* __restrict__ WbT,
    const float* __restrict__ a_self, const float* __restrict__ a_neigh,
    const float* __restrict__ A,
    unsigned short* __restrict__ featsb,
    float* __restrict__ s_self, float* __restrict__ s_neigh,
    float* __restrict__ colsum,
    unsigned short* __restrict__ edges, int* __restrict__ degs) {
  __shared__ unsigned short sX[2][64 * 72];
  __shared__ unsigned short sW[2][64 * 72];
  __shared__ float sred[4][64];
  const int bid = blockIdx.x;
  const int tid = threadIdx.x;
  const int wid = tid >> 6, lane = tid & 63;

  if (bid >= GEMM_BLOCKS) {
    const int i = bid - GEMM_BLOCKS;
    int* wave_tot = reinterpret_cast<int*>(&sred[0][0]);
    const float4* __restrict__ Arow4 =
        reinterpret_cast<const float4*>(A + (size_t)i * N_NODES);
    float4 v[4];
#pragma unroll
    for (int q = 0; q < 4; ++q) v[q] = Arow4[tid * 4 + q];
    int mask16 = 0;
#pragma unroll
    for (int q = 0; q < 4; ++q) {
      mask16 |= (v[q].x != 0.f) ? (1 << (q * 4 + 0)) : 0;
      mask16 |= (v[q].y != 0.f) ? (1 << (q * 4 + 1)) : 0;
      mask16 |= (v[q].z != 0.f) ? (1 << (q * 4 + 2)) : 0;
      mask16 |= (v[q].w != 0.f) ? (1 << (q * 4 + 3)) : 0;
    }
    int cnt = __popc(mask16);
    int inc = cnt;
#pragma unroll
    for (int s = 1; s < 64; s <<= 1) {
      int t = __shfl_up(inc, s, 64);
      if (lane >= s) inc += t;
    }
    if (lane == 63) wave_tot[wid] = inc;
    __syncthreads();
    int wprefix = 0, tot = 0;
#pragma unroll
    for (int w = 0; w < 4; ++w) {
      int t = wave_tot[w];
      if (w < wid) wprefix += t;
      tot += t;
    }
    int pos = wprefix + inc - cnt;
    const int jbase = tid * 16;
    unsigned short* __restrict__ erow = edges + (size_t)i * MAXE;
    while (mask16) {
      int k = __ffs(mask16) - 1;
      mask16 &= mask16 - 1;
      if (pos < MAXE) erow[pos] = (unsigned short)(jbase + k);
      ++pos;
    }
    if (tid == 0) degs[i] = tot < MAXE ? tot : MAXE;
    return;
  }

  const int h = bid >> 6;
  const int n0 = (bid & 63) * 64;
  const int l15 = lane & 15, l4 = lane >> 4;

  const int row = tid >> 2, seg = (tid & 3) * 16;
  const unsigned short* xsrc = Xb + (size_t)(n0 + row) * F_IN + seg;
  const unsigned short* wsrc = WbT + ((size_t)h * FHD + row) * F_IN + seg;
  const int soff = row * 72 + seg;

  f32x4 acc[4];
#pragma unroll
  for (int j = 0; j < 4; ++j) acc[j] = (f32x4){0.f, 0.f, 0.f, 0.f};

  *(bf16x8*)&sX[0][soff] = *(const bf16x8*)(xsrc);
  *(bf16x8*)&sX[0][soff + 8] = *(const bf16x8*)(xsrc + 8);
  *(bf16x8*)&sW[0][soff] = *(const bf16x8*)(wsrc);
  *(bf16x8*)&sW[0][soff + 8] = *(const bf16x8*)(wsrc + 8);
  __syncthreads();

  int cur = 0;
  for (int s = 0; s < 8; ++s) {
    bf16x8 px0, px1, pw0, pw1;
    const bool pf = (s < 7);
    if (pf) {
      const int k = (s + 1) * 64;
      px0 = *(const bf16x8*)(xsrc + k);
      px1 = *(const bf16x8*)(xsrc + k + 8);
      pw0 = *(const bf16x8*)(wsrc + k);
      pw1 = *(const bf16x8*)(wsrc + k + 8);
    }
#pragma unroll
    for (int kk = 0; kk < 2; ++kk) {
      bf16x8 a = *(const bf16x8*)&sX[cur][(wid * 16 + l15) * 72 + kk * 32 + l4 * 8];
#pragma unroll
      for (int tn = 0; tn < 4; ++tn) {
        bf16x8 b = *(const bf16x8*)&sW[cur][(tn * 16 + l15) * 72 + kk * 32 + l4 * 8];
        acc[tn] =
            __builtin_amdgcn_mfma_f32_16x16x32_bf16(a, b, acc[tn], 0, 0, 0);
      }
    }
    if (pf) {
      *(bf16x8*)&sX[cur ^ 1][soff] = px0;
      *(bf16x8*)&sX[cur ^ 1][soff + 8] = px1;
      *(bf16x8*)&sW[cur ^ 1][soff] = pw0;
      *(bf16x8*)&sW[cur ^ 1][soff + 8] = pw1;
      __syncthreads();
      cur ^= 1;
    }
  }

  float aS[4], aN[4];
#pragma unroll
  for (int tn = 0; tn < 4; ++tn) {
    aS[tn] = a_self[h * FHD + tn * 16 + l15];
    aN[tn] = a_neigh[h * FHD + tn * 16 + l15];
  }
#pragma unroll
  for (int r = 0; r < 4; ++r) {
    const int grow = n0 + wid * 16 + l4 * 4 + r;
#pragma unroll
    for (int tn = 0; tn < 4; ++tn)
      featsb[(size_t)grow * C_OUT + h * FHD + tn * 16 + l15] =
          f2bf(acc[tn][r]);
    float ps = 0.f, pn = 0.f;
#pragma unroll
    for (int tn = 0; tn < 4; ++tn) {
      float v = acc[tn][r];
      ps = fmaf(v, aS[tn], ps);
      pn = fmaf(v, aN[tn], pn);
    }
#pragma unroll
    for (int sh = 1; sh < 16; sh <<= 1) {
      ps += __shfl_xor(ps, sh, 64);
      pn += __shfl_xor(pn, sh, 64);
    }
    if (l15 == 0) {
      s_self[grow * 8 + h] = ps;
      s_neigh[grow * 8 + h] = pn;
    }
  }

  float psum[4];
#pragma unroll
  for (int tn = 0; tn < 4; ++tn) {
    float s = acc[tn][0] + acc[tn][1] + acc[tn][2] + acc[tn][3];
    s += __shfl_xor(s, 16, 64);
    s += __shfl_xor(s, 32, 64);
    psum[tn] = s;
  }
  __syncthreads();
  if (l4 == 0) {
#pragma unroll
    for (int tn = 0; tn < 4; ++tn) sred[wid][tn * 16 + l15] = psum[tn];
  }
  __syncthreads();
  if (tid < 64) {
    float s = sred[0][tid] + sred[1][tid] + sred[2][tid] + sred[3][tid];
    atomicAdd(&colsum[h * FHD + tid], s);
  }
}

// ---------------------------------------------------------------------------
// attn v5: 256 threads/block, one block per row i.
// Gather: thread owns 8 cols (ONE 16B load/edge); wave q of 4 owns edge
// quarter q (no divergence, chain ~20 deep); manual unroll-2 -> 2KB in
// flight/wave. Combine via padded s_part. Nontemporal out stores keep
// featsb L2-resident.
// ---------------------------------------------------------------------------
__global__ __launch_bounds__(256) void attn_kernel(
    const unsigned short* __restrict__ edges, const int* __restrict__ degs,
    const unsigned short* __restrict__ featsb,
    const float* __restrict__ s_self, const float* __restrict__ s_neigh,
    const float* __restrict__ colsum, const float* __restrict__ bias,
    float* __restrict__ out) {
  const int i = blockIdx.x;
  const int tid = threadIdx.x;
  const int wid = tid >> 6, lane = tid & 63;
  __shared__ int s_idx[MAXE];
  __shared__ int s_off[MAXE];          // j*1024 byte offsets
  __shared__ float s_w[H_HEADS][MAXE_P];
  __shared__ float sh_self[8];
  __shared__ float sh_e0[8], sh_invZ[8];
  __shared__ float s_part[3][64][9];   // pad 9: conflict-free b128 rd/wr

  const int deg = degs[i];
  if (tid < 8) sh_self[tid] = s_self[i * 8 + tid];
  if (tid < deg) {
    int j = edges[(size_t)i * MAXE + tid];
    s_idx[tid] = j;
    s_off[tid] = j << 10;
  }
  __syncthreads();

  // Phase 1: logits, head-major
  for (int k = tid; k < deg * 8; k += 256) {
    int e = k >> 3, h = k & 7;
    int j = s_idx[e];
    float l = sh_self[h] + s_neigh[j * 8 + h];
    s_w[h][e] = l > 0.f ? l : ALPHA * l;
  }
  __syncthreads();

  // Phase 2: per-head softmax stats; wave wid owns heads 2wid, 2wid+1
#pragma unroll
  for (int p = 0; p < 2; ++p) {
    const int h = wid * 2 + p;
    float m = -1e30f;
    for (int e = lane; e < deg; e += 64) m = fmaxf(m, s_w[h][e]);
#pragma unroll
    for (int s = 32; s > 0; s >>= 1) m = fmaxf(m, __shfl_xor(m, s, 64));
    m = fmaxf(m, 0.0f);  // non-edge dense entries are exactly 0
    float e0 = __expf(-m);
    float zs = 0.f;
    for (int e = lane; e < deg; e += 64) {
      float w = __expf(s_w[h][e] - m);
      s_w[h][e] = w - e0;  // minus colsum-correction share
      zs += w;
    }
#pragma unroll
    for (int s = 32; s > 0; s >>= 1) zs += __shfl_xor(zs, s, 64);
    if (lane == 0) {
      sh_e0[h] = e0;
      sh_invZ[h] = 1.0f / (zs + (float)(N_NODES - deg) * e0);
    }
  }
  __syncthreads();

  // Phase 3: gather. co = column oct (8 cols, 16B), wave wid = edge quarter.
  const int co = lane;
  const int q = wid;
  const int h = co >> 3;
  const int dq = (deg + 3) >> 2;
  const int ebeg = q * dq;
  const int eend = (ebeg + dq) < deg ? (ebeg + dq) : deg;
  const char* __restrict__ fbase =
      reinterpret_cast<const char*>(featsb) + co * 16;
  float a0 = 0.f, a1 = 0.f, a2 = 0.f, a3 = 0.f;
  float a4 = 0.f, a5 = 0.f, a6 = 0.f, a7 = 0.f;
  float c0 = 0.f, c1 = 0.f, c2 = 0.f, c3 = 0.f;
  float c4 = 0.f, c5 = 0.f, c6 = 0.f, c7 = 0.f;
  int e = ebeg;
  for (; e + 1 < eend; e += 2) {
    float w0 = s_w[h][e], w1 = s_w[h][e + 1];
    int o0 = s_off[e], o1 = s_off[e + 1];
    uint4 u0 = *reinterpret_cast<const uint4*>(fbase + o0);
    uint4 u1 = *reinterpret_cast<const uint4*>(fbase + o1);
    a0 = fmaf(w0, __uint_as_float(u0.x << 16), a0);
    a1 = fmaf(w0, __uint_as_float(u0.x & 0xFFFF0000u), a1);
    a2 = fmaf(w0, __uint_as_float(u0.y << 16), a2);
    a3 = fmaf(w0, __uint_as_float(u0.y & 0xFFFF0000u), a3);
    a4 = fmaf(w0, __uint_as_float(u0.z << 16), a4);
    a5 = fmaf(w0, __uint_as_float(u0.z & 0xFFFF0000u), a5);
    a6 = fmaf(w0, __uint_as_float(u0.w << 16), a6);
    a7 = fmaf(w0, __uint_as_float(u0.w & 0xFFFF0000u), a7);
    c0 = fmaf(w1, __uint_as_float(u1.x << 16), c0);
    c1 = fmaf(w1, __uint_as_float(u1.x & 0xFFFF0000u), c1);
    c2 = fmaf(w1, __uint_as_float(u1.y << 16), c2);
    c3 = fmaf(w1, __uint_as_float(u1.y & 0xFFFF0000u), c3);
    c4 = fmaf(w1, __uint_as_float(u1.z << 16), c4);
    c5 = fmaf(w1, __uint_as_float(u1.z & 0xFFFF0000u), c5);
    c6 = fmaf(w1, __uint_as_float(u1.w << 16), c6);
    c7 = fmaf(w1, __uint_as_float(u1.w & 0xFFFF0000u), c7);
  }
  if (e < eend) {
    float w0 = s_w[h][e];
    uint4 u0 = *reinterpret_cast<const uint4*>(fbase + s_off[e]);
    a0 = fmaf(w0, __uint_as_float(u0.x << 16), a0);
    a1 = fmaf(w0, __uint_as_float(u0.x & 0xFFFF0000u), a1);
    a2 = fmaf(w0, __uint_as_float(u0.y << 16), a2);
    a3 = fmaf(w0, __uint_as_float(u0.y & 0xFFFF0000u), a3);
    a4 = fmaf(w0, __uint_as_float(u0.z << 16), a4);
    a5 = fmaf(w0, __uint_as_float(u0.z & 0xFFFF0000u), a5);
    a6 = fmaf(w0, __uint_as_float(u0.w << 16), a6);
    a7 = fmaf(w0, __uint_as_float(u0.w & 0xFFFF0000u), a7);
  }
  a0 += c0; a1 += c1; a2 += c2; a3 += c3;
  a4 += c4; a5 += c5; a6 += c6; a7 += c7;

  if (q > 0) {
    float* p = &s_part[q - 1][co][0];
    p[0] = a0; p[1] = a1; p[2] = a2; p[3] = a3;
    p[4] = a4; p[5] = a5; p[6] = a6; p[7] = a7;
  }
  __syncthreads();
  if (q == 0) {
#pragma unroll
    for (int pp = 0; pp < 3; ++pp) {
      const float* p = &s_part[pp][co][0];
      a0 += p[0]; a1 += p[1]; a2 += p[2]; a3 += p[3];
      a4 += p[4]; a5 += p[5]; a6 += p[6]; a7 += p[7];
    }
    const float e0 = sh_e0[h], invZ = sh_invZ[h];
    const float4 cs0 = *reinterpret_cast<const float4*>(&colsum[co * 8]);
    const float4 cs1 = *reinterpret_cast<const float4*>(&colsum[co * 8 + 4]);
    const float4 bb0 = *reinterpret_cast<const float4*>(&bias[co * 8]);
    const float4 bb1 = *reinterpret_cast<const float4*>(&bias[co * 8 + 4]);
    f32x4 o0, o1;
    float v;
    v = (a0 + e0 * cs0.x) * invZ + bb0.x; o0.x = v > 0.f ? v : 0.f;
    v = (a1 + e0 * cs0.y) * invZ + bb0.y; o0.y = v > 0.f ? v : 0.f;
    v = (a2 + e0 * cs0.z) * invZ + bb0.z; o0.z = v > 0.f ? v : 0.f;
    v = (a3 + e0 * cs0.w) * invZ + bb0.w; o0.w = v > 0.f ? v : 0.f;
    v = (a4 + e0 * cs1.x) * invZ + bb1.x; o1.x = v > 0.f ? v : 0.f;
    v = (a5 + e0 * cs1.y) * invZ + bb1.y; o1.y = v > 0.f ? v : 0.f;
    v = (a6 + e0 * cs1.z) * invZ + bb1.z; o1.z = v > 0.f ? v : 0.f;
    v = (a7 + e0 * cs1.w) * invZ + bb1.w; o1.w = v > 0.f ? v : 0.f;
    f32x4* dst = reinterpret_cast<f32x4*>(&out[(size_t)i * C_OUT + co * 8]);
    __builtin_nontemporal_store(o0, dst);
    __builtin_nontemporal_store(o1, dst + 1);
  }
}

extern "C" void kernel_launch(void* const* d_in, const int* in_sizes, int n_in,
                              void* d_out, int out_size, void* d_ws, size_t ws_size,
                              hipStream_t stream) {
  const float* X = (const float*)d_in[0];
  const float* A = (const float*)d_in[1];
  const float* W = (const float*)d_in[2];
  const float* a_self = (const float*)d_in[3];
  const float* a_neigh = (const float*)d_in[4];
  const float* b = (const float*)d_in[5];
  float* out = (float*)d_out;

  char* ws = (char*)d_ws;
  unsigned short* featsb = (unsigned short*)ws;               // 4 MB
  char* p = ws + (size_t)N_NODES * C_OUT * 2;
  float* s_self = (float*)p;  p += N_NODES * H_HEADS * 4;     // 128 KB
  float* s_neigh = (float*)p; p += N_NODES * H_HEADS * 4;     // 128 KB
  float* colsum = (float*)p;  p += C_OUT * 4;                 // 2 KB
  int* degs = (int*)p;        p += N_NODES * 4;               // 16 KB
  unsigned short* edges = (unsigned short*)p;
  p += (size_t)N_NODES * MAXE * 2;                            // 1.5 MB
  unsigned short* WbT = (unsigned short*)p;                   // 512 KB

  // Xb parked in d_out (4 MB of its 8 MB); attn fully overwrites d_out later.
  unsigned short* Xb = (unsigned short*)d_out;

  conv_kernel<<<2048 + 64 + 1, 256, 0, stream>>>(X, W, Xb, WbT, colsum);
  gemm_scan_kernel<<<GEMM_BLOCKS + N_NODES, 256, 0, stream>>>(
      Xb, WbT, a_self, a_neigh, A, featsb, s_self, s_neigh, colsum, edges,
      degs);
  attn_kernel<<<N_NODES, 256, 0, stream>>>(edges, degs, featsb, s_self,
                                           s_neigh, colsum, b, out);
}

// Round 14
// 51.561 us; speedup vs baseline: 1.2487x; 1.0036x over previous
//
#include <hip/hip_runtime.h>
#include <hip/hip_bf16.h>

#define N_NODES 4096
#define F_IN 512
#define FHD 64
#define H_HEADS 8
#define C_OUT 512   /* H*FH */
#define ALPHA 0.2f
#define MAXE 192
#define MAXE_P 200  /* head-major weight row stride: conflict-free */
#define GEMM_BLOCKS 512

typedef __attribute__((ext_vector_type(8))) short bf16x8;
typedef __attribute__((ext_vector_type(4))) float f32x4;

static __device__ __forceinline__ unsigned short f2bf(float f) {
  __hip_bfloat16 h = __float2bfloat16(f);
  union { __hip_bfloat16 h; unsigned short u; } cvt;
  cvt.h = h;
  return cvt.u;
}

// ---------------------------------------------------------------------------
// conv: blocks [0,64) W transpose->bf16 | 64: zero colsum. Tiny (~2us).
// (X is converted in-GEMM during staging now; no convX pass.)
// ---------------------------------------------------------------------------
__global__ __launch_bounds__(256) void conv_kernel(
    const float* __restrict__ W, unsigned short* __restrict__ WbT,
    float* __restrict__ colsum) {
  __shared__ float sT[64][65];
  const int bid = blockIdx.x;
  const int tid = threadIdx.x;
  if (bid < 64) {
    const int fblk = bid & 7, h = bid >> 3;
#pragma unroll
    for (int i = 0; i < 16; ++i) {
      int idx = tid + i * 256;
      int f = idx >> 6, o = idx & 63;
      sT[f][o] = W[((size_t)h * F_IN + fblk * 64 + f) * FHD + o];
    }
    __syncthreads();
#pragma unroll
    for (int i = 0; i < 16; ++i) {
      int idx = tid + i * 256;
      int o = idx >> 6, f = idx & 63;
      WbT[(size_t)h * FHD * F_IN + (size_t)o * F_IN + fblk * 64 + f] =
          f2bf(sT[f][o]);
    }
  } else {
    colsum[tid] = 0.f;
    colsum[tid + 256] = 0.f;
  }
}

// ---------------------------------------------------------------------------
// gemm_scan: blocks [0,512) MFMA GEMM (64 rows x 1 head, BK=64, dbuf;
// X staged f32->bf16 in-kernel — the cvt VALU hides under the scan's HBM
// stream); blocks [512,4608) A-row CSR scan. Co-resident (R8-proven).
// ---------------------------------------------------------------------------
__global__ __launch_bounds__(256) void gemm_scan_kernel(
    const float* __restrict__ X, const unsigned short* __restrict__ WbT,
    const float* __restrict__ a_self, const float* __restrict__ a_neigh,
    const float* __restrict__ A,
    unsigned short* __restrict__ featsb,
    float* __restrict__ s_self, float* __restrict__ s_neigh,
    float* __restrict__ colsum,
    unsigned short* __restrict__ edges, int* __restrict__ degs) {
  __shared__ unsigned short sX[2][64 * 72];
  __shared__ unsigned short sW[2][64 * 72];
  __shared__ float sred[4][64];
  const int bid = blockIdx.x;
  const int tid = threadIdx.x;
  const int wid = tid >> 6, lane = tid & 63;

  if (bid >= GEMM_BLOCKS) {
    // ---- scan path: CSR build for row i
    const int i = bid - GEMM_BLOCKS;
    int* wave_tot = reinterpret_cast<int*>(&sred[0][0]);
    const float4* __restrict__ Arow4 =
        reinterpret_cast<const float4*>(A + (size_t)i * N_NODES);
    float4 v[4];
#pragma unroll
    for (int q = 0; q < 4; ++q) v[q] = Arow4[tid * 4 + q];
    int mask16 = 0;
#pragma unroll
    for (int q = 0; q < 4; ++q) {
      mask16 |= (v[q].x != 0.f) ? (1 << (q * 4 + 0)) : 0;
      mask16 |= (v[q].y != 0.f) ? (1 << (q * 4 + 1)) : 0;
      mask16 |= (v[q].z != 0.f) ? (1 << (q * 4 + 2)) : 0;
      mask16 |= (v[q].w != 0.f) ? (1 << (q * 4 + 3)) : 0;
    }
    int cnt = __popc(mask16);
    int inc = cnt;
#pragma unroll
    for (int s = 1; s < 64; s <<= 1) {
      int t = __shfl_up(inc, s, 64);
      if (lane >= s) inc += t;
    }
    if (lane == 63) wave_tot[wid] = inc;
    __syncthreads();
    int wprefix = 0, tot = 0;
#pragma unroll
    for (int w = 0; w < 4; ++w) {
      int t = wave_tot[w];
      if (w < wid) wprefix += t;
      tot += t;
    }
    int pos = wprefix + inc - cnt;
    const int jbase = tid * 16;
    unsigned short* __restrict__ erow = edges + (size_t)i * MAXE;
    while (mask16) {
      int k = __ffs(mask16) - 1;
      mask16 &= mask16 - 1;
      if (pos < MAXE) erow[pos] = (unsigned short)(jbase + k);
      ++pos;
    }
    if (tid == 0) degs[i] = tot < MAXE ? tot : MAXE;
    return;
  }

  // ---- GEMM path
  const int h = bid >> 6;
  const int n0 = (bid & 63) * 64;
  const int l15 = lane & 15, l4 = lane >> 4;

  const int row = tid >> 2, seg = (tid & 3) * 16;
  const float* xsrc = X + (size_t)(n0 + row) * F_IN + seg;
  const unsigned short* wsrc = WbT + ((size_t)h * FHD + row) * F_IN + seg;
  const int soff = row * 72 + seg;

  f32x4 acc[4];
#pragma unroll
  for (int j = 0; j < 4; ++j) acc[j] = (f32x4){0.f, 0.f, 0.f, 0.f};

  // stage K-step 0 (X converted f32->bf16 here)
  {
    float4 xa = *(const float4*)(xsrc);
    float4 xb = *(const float4*)(xsrc + 4);
    float4 xc = *(const float4*)(xsrc + 8);
    float4 xd = *(const float4*)(xsrc + 12);
    bf16x8 p0, p1;
    p0[0] = f2bf(xa.x); p0[1] = f2bf(xa.y); p0[2] = f2bf(xa.z); p0[3] = f2bf(xa.w);
    p0[4] = f2bf(xb.x); p0[5] = f2bf(xb.y); p0[6] = f2bf(xb.z); p0[7] = f2bf(xb.w);
    p1[0] = f2bf(xc.x); p1[1] = f2bf(xc.y); p1[2] = f2bf(xc.z); p1[3] = f2bf(xc.w);
    p1[4] = f2bf(xd.x); p1[5] = f2bf(xd.y); p1[6] = f2bf(xd.z); p1[7] = f2bf(xd.w);
    *(bf16x8*)&sX[0][soff] = p0;
    *(bf16x8*)&sX[0][soff + 8] = p1;
    *(bf16x8*)&sW[0][soff] = *(const bf16x8*)(wsrc);
    *(bf16x8*)&sW[0][soff + 8] = *(const bf16x8*)(wsrc + 8);
  }
  __syncthreads();

  int cur = 0;
  for (int s = 0; s < 8; ++s) {
    float4 xa, xb, xc, xd;
    bf16x8 pw0, pw1;
    const bool pf = (s < 7);
    if (pf) {
      const int k = (s + 1) * 64;
      xa = *(const float4*)(xsrc + k);
      xb = *(const float4*)(xsrc + k + 4);
      xc = *(const float4*)(xsrc + k + 8);
      xd = *(const float4*)(xsrc + k + 12);
      pw0 = *(const bf16x8*)(wsrc + k);
      pw1 = *(const bf16x8*)(wsrc + k + 8);
    }
#pragma unroll
    for (int kk = 0; kk < 2; ++kk) {
      bf16x8 a = *(const bf16x8*)&sX[cur][(wid * 16 + l15) * 72 + kk * 32 + l4 * 8];
#pragma unroll
      for (int tn = 0; tn < 4; ++tn) {
        bf16x8 b = *(const bf16x8*)&sW[cur][(tn * 16 + l15) * 72 + kk * 32 + l4 * 8];
        acc[tn] =
            __builtin_amdgcn_mfma_f32_16x16x32_bf16(a, b, acc[tn], 0, 0, 0);
      }
    }
    if (pf) {
      bf16x8 p0, p1;
      p0[0] = f2bf(xa.x); p0[1] = f2bf(xa.y); p0[2] = f2bf(xa.z); p0[3] = f2bf(xa.w);
      p0[4] = f2bf(xb.x); p0[5] = f2bf(xb.y); p0[6] = f2bf(xb.z); p0[7] = f2bf(xb.w);
      p1[0] = f2bf(xc.x); p1[1] = f2bf(xc.y); p1[2] = f2bf(xc.z); p1[3] = f2bf(xc.w);
      p1[4] = f2bf(xd.x); p1[5] = f2bf(xd.y); p1[6] = f2bf(xd.z); p1[7] = f2bf(xd.w);
      *(bf16x8*)&sX[cur ^ 1][soff] = p0;
      *(bf16x8*)&sX[cur ^ 1][soff + 8] = p1;
      *(bf16x8*)&sW[cur ^ 1][soff] = pw0;
      *(bf16x8*)&sW[cur ^ 1][soff + 8] = pw1;
      __syncthreads();
      cur ^= 1;
    }
  }

  float aS[4], aN[4];
#pragma unroll
  for (int tn = 0; tn < 4; ++tn) {
    aS[tn] = a_self[h * FHD + tn * 16 + l15];
    aN[tn] = a_neigh[h * FHD + tn * 16 + l15];
  }
#pragma unroll
  for (int r = 0; r < 4; ++r) {
    const int grow = n0 + wid * 16 + l4 * 4 + r;
#pragma unroll
    for (int tn = 0; tn < 4; ++tn)
      featsb[(size_t)grow * C_OUT + h * FHD + tn * 16 + l15] =
          f2bf(acc[tn][r]);
    float ps = 0.f, pn = 0.f;
#pragma unroll
    for (int tn = 0; tn < 4; ++tn) {
      float v = acc[tn][r];
      ps = fmaf(v, aS[tn], ps);
      pn = fmaf(v, aN[tn], pn);
    }
#pragma unroll
    for (int sh = 1; sh < 16; sh <<= 1) {
      ps += __shfl_xor(ps, sh, 64);
      pn += __shfl_xor(pn, sh, 64);
    }
    if (l15 == 0) {
      s_self[grow * 8 + h] = ps;
      s_neigh[grow * 8 + h] = pn;
    }
  }

  float psum[4];
#pragma unroll
  for (int tn = 0; tn < 4; ++tn) {
    float s = acc[tn][0] + acc[tn][1] + acc[tn][2] + acc[tn][3];
    s += __shfl_xor(s, 16, 64);
    s += __shfl_xor(s, 32, 64);
    psum[tn] = s;
  }
  __syncthreads();
  if (l4 == 0) {
#pragma unroll
    for (int tn = 0; tn < 4; ++tn) sred[wid][tn * 16 + l15] = psum[tn];
  }
  __syncthreads();
  if (tid < 64) {
    float s = sred[0][tid] + sred[1][tid] + sred[2][tid] + sred[3][tid];
    atomicAdd(&colsum[h * FHD + tid], s);
  }
}

// ---------------------------------------------------------------------------
// attn v6: 256 threads/block, one block per row i. Gather unroll-4:
// 4x16B loads in flight per wave iteration (4KB/wave) into two chain-sets.
// ---------------------------------------------------------------------------
__global__ __launch_bounds__(256) void attn_kernel(
    const unsigned short* __restrict__ edges, const int* __restrict__ degs,
    const unsigned short* __restrict__ featsb,
    const float* __restrict__ s_self, const float* __restrict__ s_neigh,
    const float* __restrict__ colsum, const float* __restrict__ bias,
    float* __restrict__ out) {
  const int i = blockIdx.x;
  const int tid = threadIdx.x;
  const int wid = tid >> 6, lane = tid & 63;
  __shared__ int s_idx[MAXE];
  __shared__ int s_off[MAXE];          // j*1024 byte offsets
  __shared__ float s_w[H_HEADS][MAXE_P];
  __shared__ float sh_self[8];
  __shared__ float sh_e0[8], sh_invZ[8];
  __shared__ float s_part[3][64][9];   // pad 9: conflict-free

  const int deg = degs[i];
  if (tid < 8) sh_self[tid] = s_self[i * 8 + tid];
  if (tid < deg) {
    int j = edges[(size_t)i * MAXE + tid];
    s_idx[tid] = j;
    s_off[tid] = j << 10;
  }
  __syncthreads();

  // Phase 1: logits, head-major
  for (int k = tid; k < deg * 8; k += 256) {
    int e = k >> 3, h = k & 7;
    int j = s_idx[e];
    float l = sh_self[h] + s_neigh[j * 8 + h];
    s_w[h][e] = l > 0.f ? l : ALPHA * l;
  }
  __syncthreads();

  // Phase 2: per-head softmax stats; wave wid owns heads 2wid, 2wid+1
#pragma unroll
  for (int p = 0; p < 2; ++p) {
    const int h = wid * 2 + p;
    float m = -1e30f;
    for (int e = lane; e < deg; e += 64) m = fmaxf(m, s_w[h][e]);
#pragma unroll
    for (int s = 32; s > 0; s >>= 1) m = fmaxf(m, __shfl_xor(m, s, 64));
    m = fmaxf(m, 0.0f);  // non-edge dense entries are exactly 0
    float e0 = __expf(-m);
    float zs = 0.f;
    for (int e = lane; e < deg; e += 64) {
      float w = __expf(s_w[h][e] - m);
      s_w[h][e] = w - e0;  // minus colsum-correction share
      zs += w;
    }
#pragma unroll
    for (int s = 32; s > 0; s >>= 1) zs += __shfl_xor(zs, s, 64);
    if (lane == 0) {
      sh_e0[h] = e0;
      sh_invZ[h] = 1.0f / (zs + (float)(N_NODES - deg) * e0);
    }
  }
  __syncthreads();

  // Phase 3: gather. co = column oct (8 cols, 16B); wave wid = edge quarter.
  const int co = lane;
  const int q = wid;
  const int h = co >> 3;
  const int dq = (deg + 3) >> 2;
  const int ebeg = q * dq;
  const int eend = (ebeg + dq) < deg ? (ebeg + dq) : deg;
  const char* __restrict__ fbase =
      reinterpret_cast<const char*>(featsb) + co * 16;
  float a0 = 0.f, a1 = 0.f, a2 = 0.f, a3 = 0.f;
  float a4 = 0.f, a5 = 0.f, a6 = 0.f, a7 = 0.f;
  float c0 = 0.f, c1 = 0.f, c2 = 0.f, c3 = 0.f;
  float c4 = 0.f, c5 = 0.f, c6 = 0.f, c7 = 0.f;
  int e = ebeg;
  for (; e + 3 < eend; e += 4) {
    float w0 = s_w[h][e], w1 = s_w[h][e + 1];
    float w2 = s_w[h][e + 2], w3 = s_w[h][e + 3];
    int o0 = s_off[e], o1 = s_off[e + 1];
    int o2 = s_off[e + 2], o3 = s_off[e + 3];
    uint4 u0 = *reinterpret_cast<const uint4*>(fbase + o0);
    uint4 u1 = *reinterpret_cast<const uint4*>(fbase + o1);
    uint4 u2 = *reinterpret_cast<const uint4*>(fbase + o2);
    uint4 u3 = *reinterpret_cast<const uint4*>(fbase + o3);
    a0 = fmaf(w0, __uint_as_float(u0.x << 16), a0);
    a1 = fmaf(w0, __uint_as_float(u0.x & 0xFFFF0000u), a1);
    a2 = fmaf(w0, __uint_as_float(u0.y << 16), a2);
    a3 = fmaf(w0, __uint_as_float(u0.y & 0xFFFF0000u), a3);
    a4 = fmaf(w0, __uint_as_float(u0.z << 16), a4);
    a5 = fmaf(w0, __uint_as_float(u0.z & 0xFFFF0000u), a5);
    a6 = fmaf(w0, __uint_as_float(u0.w << 16), a6);
    a7 = fmaf(w0, __uint_as_float(u0.w & 0xFFFF0000u), a7);
    c0 = fmaf(w1, __uint_as_float(u1.x << 16), c0);
    c1 = fmaf(w1, __uint_as_float(u1.x & 0xFFFF0000u), c1);
    c2 = fmaf(w1, __uint_as_float(u1.y << 16), c2);
    c3 = fmaf(w1, __uint_as_float(u1.y & 0xFFFF0000u), c3);
    c4 = fmaf(w1, __uint_as_float(u1.z << 16), c4);
    c5 = fmaf(w1, __uint_as_float(u1.z & 0xFFFF0000u), c5);
    c6 = fmaf(w1, __uint_as_float(u1.w << 16), c6);
    c7 = fmaf(w1, __uint_as_float(u1.w & 0xFFFF0000u), c7);
    a0 = fmaf(w2, __uint_as_float(u2.x << 16), a0);
    a1 = fmaf(w2, __uint_as_float(u2.x & 0xFFFF0000u), a1);
    a2 = fmaf(w2, __uint_as_float(u2.y << 16), a2);
    a3 = fmaf(w2, __uint_as_float(u2.y & 0xFFFF0000u), a3);
    a4 = fmaf(w2, __uint_as_float(u2.z << 16), a4);
    a5 = fmaf(w2, __uint_as_float(u2.z & 0xFFFF0000u), a5);
    a6 = fmaf(w2, __uint_as_float(u2.w << 16), a6);
    a7 = fmaf(w2, __uint_as_float(u2.w & 0xFFFF0000u), a7);
    c0 = fmaf(w3, __uint_as_float(u3.x << 16), c0);
    c1 = fmaf(w3, __uint_as_float(u3.x & 0xFFFF0000u), c1);
    c2 = fmaf(w3, __uint_as_float(u3.y << 16), c2);
    c3 = fmaf(w3, __uint_as_float(u3.y & 0xFFFF0000u), c3);
    c4 = fmaf(w3, __uint_as_float(u3.z << 16), c4);
    c5 = fmaf(w3, __uint_as_float(u3.z & 0xFFFF0000u), c5);
    c6 = fmaf(w3, __uint_as_float(u3.w << 16), c6);
    c7 = fmaf(w3, __uint_as_float(u3.w & 0xFFFF0000u), c7);
  }
  for (; e < eend; ++e) {
    float w0 = s_w[h][e];
    uint4 u0 = *reinterpret_cast<const uint4*>(fbase + s_off[e]);
    a0 = fmaf(w0, __uint_as_float(u0.x << 16), a0);
    a1 = fmaf(w0, __uint_as_float(u0.x & 0xFFFF0000u), a1);
    a2 = fmaf(w0, __uint_as_float(u0.y << 16), a2);
    a3 = fmaf(w0, __uint_as_float(u0.y & 0xFFFF0000u), a3);
    a4 = fmaf(w0, __uint_as_float(u0.z << 16), a4);
    a5 = fmaf(w0, __uint_as_float(u0.z & 0xFFFF0000u), a5);
    a6 = fmaf(w0, __uint_as_float(u0.w << 16), a6);
    a7 = fmaf(w0, __uint_as_float(u0.w & 0xFFFF0000u), a7);
  }
  a0 += c0; a1 += c1; a2 += c2; a3 += c3;
  a4 += c4; a5 += c5; a6 += c6; a7 += c7;

  if (q > 0) {
    float* p = &s_part[q - 1][co][0];
    p[0] = a0; p[1] = a1; p[2] = a2; p[3] = a3;
    p[4] = a4; p[5] = a5; p[6] = a6; p[7] = a7;
  }
  __syncthreads();
  if (q == 0) {
#pragma unroll
    for (int pp = 0; pp < 3; ++pp) {
      const float* p = &s_part[pp][co][0];
      a0 += p[0]; a1 += p[1]; a2 += p[2]; a3 += p[3];
      a4 += p[4]; a5 += p[5]; a6 += p[6]; a7 += p[7];
    }
    const float e0 = sh_e0[h], invZ = sh_invZ[h];
    const float4 cs0 = *reinterpret_cast<const float4*>(&colsum[co * 8]);
    const float4 cs1 = *reinterpret_cast<const float4*>(&colsum[co * 8 + 4]);
    const float4 bb0 = *reinterpret_cast<const float4*>(&bias[co * 8]);
    const float4 bb1 = *reinterpret_cast<const float4*>(&bias[co * 8 + 4]);
    f32x4 o0, o1;
    float v;
    v = (a0 + e0 * cs0.x) * invZ + bb0.x; o0.x = v > 0.f ? v : 0.f;
    v = (a1 + e0 * cs0.y) * invZ + bb0.y; o0.y = v > 0.f ? v : 0.f;
    v = (a2 + e0 * cs0.z) * invZ + bb0.z; o0.z = v > 0.f ? v : 0.f;
    v = (a3 + e0 * cs0.w) * invZ + bb0.w; o0.w = v > 0.f ? v : 0.f;
    v = (a4 + e0 * cs1.x) * invZ + bb1.x; o1.x = v > 0.f ? v : 0.f;
    v = (a5 + e0 * cs1.y) * invZ + bb1.y; o1.y = v > 0.f ? v : 0.f;
    v = (a6 + e0 * cs1.z) * invZ + bb1.z; o1.z = v > 0.f ? v : 0.f;
    v = (a7 + e0 * cs1.w) * invZ + bb1.w; o1.w = v > 0.f ? v : 0.f;
    f32x4* dst = reinterpret_cast<f32x4*>(&out[(size_t)i * C_OUT + co * 8]);
    __builtin_nontemporal_store(o0, dst);
    __builtin_nontemporal_store(o1, dst + 1);
  }
}

extern "C" void kernel_launch(void* const* d_in, const int* in_sizes, int n_in,
                              void* d_out, int out_size, void* d_ws, size_t ws_size,
                              hipStream_t stream) {
  const float* X = (const float*)d_in[0];
  const float* A = (const float*)d_in[1];
  const float* W = (const float*)d_in[2];
  const float* a_self = (const float*)d_in[3];
  const float* a_neigh = (const float*)d_in[4];
  const float* b = (const float*)d_in[5];
  float* out = (float*)d_out;

  char* ws = (char*)d_ws;
  unsigned short* featsb = (unsigned short*)ws;               // 4 MB
  char* p = ws + (size_t)N_NODES * C_OUT * 2;
  float* s_self = (float*)p;  p += N_NODES * H_HEADS * 4;     // 128 KB
  float* s_neigh = (float*)p; p += N_NODES * H_HEADS * 4;     // 128 KB
  float* colsum = (float*)p;  p += C_OUT * 4;                 // 2 KB
  int* degs = (int*)p;        p += N_NODES * 4;               // 16 KB
  unsigned short* edges = (unsigned short*)p;
  p += (size_t)N_NODES * MAXE * 2;                            // 1.5 MB
  unsigned short* WbT = (unsigned short*)p;                   // 512 KB

  conv_kernel<<<65, 256, 0, stream>>>(W, WbT, colsum);
  gemm_scan_kernel<<<GEMM_BLOCKS + N_NODES, 256, 0, stream>>>(
      X, WbT, a_self, a_neigh, A, featsb, s_self, s_neigh, colsum, edges,
      degs);
  attn_kernel<<<N_NODES, 256, 0, stream>>>(edges, degs, featsb, s_self,
                                           s_neigh, colsum, b, out);
}